// Round 1
// baseline (1995.034 us; speedup 1.0000x reference)
//
#include <hip/hip_runtime.h>
#include <hip/hip_bf16.h>
#include <math.h>

#define HID 64
#define NODE_BLK 128

// ---------------------------------------------------------------------------
// Node-side MLP: for each node n:
//   g1 = relu(x[n] @ W1 + b1);  u[n] = g1 @ A_top
//   g2 = relu(x[n] @ W2 + b2);  v[n] = g2 @ A_bot
// Also accumulates `out` (mode 0: out = x, mode 1: out += x).
// Mapping: thread = node. x row staged transposed in LDS [k][tid] so the
// dynamic-k loop reads per-lane LDS (conflict-free, stride-1 across lanes);
// W rows are wave-uniform float4 loads (scalarizable). 64 f32 accumulators.
// ---------------------------------------------------------------------------

__device__ __forceinline__ void gemv_pair(
    const float (*src)[NODE_BLK],   // staged input  [64][NODE_BLK]
    float (*gbuf)[NODE_BLK],        // staged hidden [64][NODE_BLK]
    const float* __restrict__ W,    // [64][64]
    const float* __restrict__ b,    // [64]
    const float* __restrict__ A,    // [64][64]
    float* __restrict__ dst,        // [n][64]
    int tid, bool active, size_t nodeOff)
{
    float acc[HID];
    #pragma unroll
    for (int q = 0; q < 16; ++q) {
        float4 bb = reinterpret_cast<const float4*>(b)[q];
        acc[4*q+0] = bb.x; acc[4*q+1] = bb.y; acc[4*q+2] = bb.z; acc[4*q+3] = bb.w;
    }
    for (int k = 0; k < HID; ++k) {
        float xk = src[k][tid];
        const float4* Wr = reinterpret_cast<const float4*>(W + (k << 6));
        #pragma unroll
        for (int q = 0; q < 16; ++q) {
            float4 w = Wr[q];
            acc[4*q+0] = fmaf(xk, w.x, acc[4*q+0]);
            acc[4*q+1] = fmaf(xk, w.y, acc[4*q+1]);
            acc[4*q+2] = fmaf(xk, w.z, acc[4*q+2]);
            acc[4*q+3] = fmaf(xk, w.w, acc[4*q+3]);
        }
    }
    // relu -> stage g (own column, no barrier needed), reset acc
    #pragma unroll
    for (int j = 0; j < HID; ++j) {
        gbuf[j][tid] = fmaxf(acc[j], 0.f);
        acc[j] = 0.f;
    }
    for (int k = 0; k < HID; ++k) {
        float gk = gbuf[k][tid];
        const float4* Ar = reinterpret_cast<const float4*>(A + (k << 6));
        #pragma unroll
        for (int q = 0; q < 16; ++q) {
            float4 w = Ar[q];
            acc[4*q+0] = fmaf(gk, w.x, acc[4*q+0]);
            acc[4*q+1] = fmaf(gk, w.y, acc[4*q+1]);
            acc[4*q+2] = fmaf(gk, w.z, acc[4*q+2]);
            acc[4*q+3] = fmaf(gk, w.w, acc[4*q+3]);
        }
    }
    if (active) {
        float4* d4 = reinterpret_cast<float4*>(dst + nodeOff);
        #pragma unroll
        for (int q = 0; q < 16; ++q) {
            float4 t;
            t.x = acc[4*q+0]; t.y = acc[4*q+1]; t.z = acc[4*q+2]; t.w = acc[4*q+3];
            d4[q] = t;
        }
    }
}

__global__ __launch_bounds__(NODE_BLK) void node_mlp_kernel(
    const float* __restrict__ x,
    const float* __restrict__ W1, const float* __restrict__ b1,
    const float* __restrict__ W2, const float* __restrict__ b2,
    const float* __restrict__ A12,   // att1_W[l]: [128][64]; top = A12, bot = A12+64*64
    float* __restrict__ u, float* __restrict__ v,
    float* __restrict__ out, int mode, int n)
{
    __shared__ float x_lds[HID][NODE_BLK];
    __shared__ float g_lds[HID][NODE_BLK];
    int tid = threadIdx.x;
    int node = blockIdx.x * NODE_BLK + tid;
    bool active = node < n;
    size_t off = (size_t)node * HID;

    if (active) {
        const float4* x4 = reinterpret_cast<const float4*>(x + off);
        float4* o4 = reinterpret_cast<float4*>(out + off);
        #pragma unroll
        for (int q = 0; q < 16; ++q) {
            float4 t = x4[q];
            x_lds[4*q+0][tid] = t.x; x_lds[4*q+1][tid] = t.y;
            x_lds[4*q+2][tid] = t.z; x_lds[4*q+3][tid] = t.w;
            if (mode) {
                float4 o = o4[q];
                o.x += t.x; o.y += t.y; o.z += t.z; o.w += t.w;
                o4[q] = o;
            } else {
                o4[q] = t;
            }
        }
    }
    gemv_pair(x_lds, g_lds, W1, b1, A12,             u, tid, active, off);
    gemv_pair(x_lds, g_lds, W2, b2, A12 + HID*HID,   v, tid, active, off);
}

// ---------------------------------------------------------------------------
// Edge pass 1: h = relu(u[row] + v[col] + att1_b); la = h . att2_W + att2_b
// mask = clip(sigmoid(la)*(ZETA-GAMMA)+GAMMA, 0, 1); rowsum[row] += mask
// 64 lanes per edge.
// ---------------------------------------------------------------------------
__global__ __launch_bounds__(256) void edge_mask_kernel(
    const float* __restrict__ u, const float* __restrict__ v,
    const float* __restrict__ ab,    // att1_b[l] [64]
    const float* __restrict__ w2,    // att2_W[l] [64]
    const float* __restrict__ b2p,   // &att2_b[l]
    const int* __restrict__ row, const int* __restrict__ col,
    float* __restrict__ mask, float* __restrict__ rowsum, int E)
{
    int gid = blockIdx.x * 256 + threadIdx.x;
    int e = gid >> 6;
    if (e >= E) return;
    int lane = threadIdx.x & 63;
    int r = row[e], c = col[e];
    float h = u[(size_t)r * HID + lane] + v[(size_t)c * HID + lane] + ab[lane];
    float p = fmaxf(h, 0.f) * w2[lane];
    #pragma unroll
    for (int off = 32; off; off >>= 1) p += __shfl_xor(p, off, 64);
    if (lane == 0) {
        float la = p + b2p[0];
        float s = 1.f / (1.f + expf(-la));
        float m = fminf(fmaxf(s * 1.5f - 0.45f, 0.f), 1.f);   // ZETA-GAMMA=1.5, GAMMA=-0.45
        mask[e] = m;
        atomicAdd(rowsum + r, m);
    }
}

// rowsum -> d_inv_sqrt in place: clip((rowsum + 1e-6)^-0.5, 0, 10)
__global__ __launch_bounds__(256) void dinv_kernel(float* __restrict__ rs, int n)
{
    int i = blockIdx.x * 256 + threadIdx.x;
    if (i >= n) return;
    float r = rs[i] + 1e-6f;
    float d = 1.f / sqrtf(r);
    rs[i] = fminf(d, 10.f);
}

// Edge pass 2: val = mask * dinv[row] * dinv[col];
// x_new[row] += val * x[col]   (64 lanes per edge, f32 atomics)
__global__ __launch_bounds__(256) void edge_agg_kernel(
    const float* __restrict__ x,
    const float* __restrict__ mask,
    const float* __restrict__ dinv,
    const int* __restrict__ row, const int* __restrict__ col,
    float* __restrict__ xnew, int E)
{
    int gid = blockIdx.x * 256 + threadIdx.x;
    int e = gid >> 6;
    if (e >= E) return;
    int lane = threadIdx.x & 63;
    int r = row[e], c = col[e];
    float val = mask[e] * dinv[r] * dinv[c];
    float xv = x[(size_t)c * HID + lane];
    atomicAdd(xnew + (size_t)r * HID + lane, val * xv);
}

__global__ __launch_bounds__(256) void final_add_kernel(
    float* __restrict__ out, const float* __restrict__ x, int n4)
{
    int i = blockIdx.x * 256 + threadIdx.x;
    if (i >= n4) return;
    float4* o = reinterpret_cast<float4*>(out) + i;
    const float4* s = reinterpret_cast<const float4*>(x) + i;
    float4 a = *o; float4 b = *s;
    a.x += b.x; a.y += b.y; a.z += b.z; a.w += b.w;
    *o = a;
}

// ---------------------------------------------------------------------------

extern "C" void kernel_launch(void* const* d_in, const int* in_sizes, int n_in,
                              void* d_out, int out_size, void* d_ws, size_t ws_size,
                              hipStream_t stream)
{
    const float* feat  = (const float*)d_in[0];
    const float* nbW   = (const float*)d_in[1];
    const float* nbb   = (const float*)d_in[2];
    const float* selfW = (const float*)d_in[3];
    const float* selfb = (const float*)d_in[4];
    const float* a1W   = (const float*)d_in[5];
    const float* a1b   = (const float*)d_in[6];
    const float* a2W   = (const float*)d_in[7];
    const float* a2b   = (const float*)d_in[8];
    const int*   row   = (const int*)d_in[9];
    const int*   col   = (const int*)d_in[10];
    float* out = (float*)d_out;

    const int n = in_sizes[0] / HID;
    const int E = in_sizes[9];
    const int L = in_sizes[1] / (HID * HID);

    const size_t NH = (size_t)n * HID;
    float* ws    = (float*)d_ws;
    float* u     = ws;
    float* v     = ws + NH;
    float* xb0   = ws + 2 * NH;
    float* xb1   = ws + 3 * NH;
    float* rsum  = ws + 4 * NH;           // n floats; becomes dinv in place
    float* maskb = ws + 4 * NH + n;       // E floats

    const int nodeBlocks = (n + NODE_BLK - 1) / NODE_BLK;
    const long long edgeTot = (long long)E * 64;
    const int edgeBlocks = (int)((edgeTot + 255) / 256);

    const float* x_in = feat;
    float* x_new = xb0;
    for (int l = 0; l < L; ++l) {
        node_mlp_kernel<<<nodeBlocks, NODE_BLK, 0, stream>>>(
            x_in,
            nbW + (size_t)l * HID * HID,   nbb + (size_t)l * HID,
            selfW + (size_t)l * HID * HID, selfb + (size_t)l * HID,
            a1W + (size_t)l * 2 * HID * HID,
            u, v, out, (l == 0) ? 0 : 1, n);

        hipMemsetAsync(rsum, 0, (size_t)n * sizeof(float), stream);
        edge_mask_kernel<<<edgeBlocks, 256, 0, stream>>>(
            u, v, a1b + (size_t)l * HID, a2W + (size_t)l * HID, a2b + l,
            row, col, maskb, rsum, E);

        dinv_kernel<<<(n + 255) / 256, 256, 0, stream>>>(rsum, n);

        hipMemsetAsync(x_new, 0, NH * sizeof(float), stream);
        edge_agg_kernel<<<edgeBlocks, 256, 0, stream>>>(
            x_in, maskb, rsum, row, col, x_new, E);

        x_in = x_new;
        x_new = (x_new == xb0) ? xb1 : xb0;
    }
    final_add_kernel<<<(int)((NH / 4 + 255) / 256), 256, 0, stream>>>(out, x_in, (int)(NH / 4));
}

// Round 2
// 1197.829 us; speedup vs baseline: 1.6655x; 1.6655x over previous
//
#include <hip/hip_runtime.h>
#include <hip/hip_bf16.h>
#include <math.h>

#define HID 64
#define NODE_BLK 128
#define SCAN_B 256

typedef __hip_bfloat16 bf16;

// ---------------------------------------------------------------------------
// Node-side MLP (thread = node):
//   g1 = relu(x@W1 + b1); u = g1 @ A_top   (stored bf16)
//   g2 = relu(x@W2 + b2); v = g2 @ A_bot   (stored bf16)
// mode 0: also out = x (feat copy). x staged transposed in LDS [k][tid].
// ---------------------------------------------------------------------------
__device__ __forceinline__ void gemv_pair(
    const float (*src)[NODE_BLK],
    float (*gbuf)[NODE_BLK],
    const float* __restrict__ W,
    const float* __restrict__ b,
    const float* __restrict__ A,
    bf16* __restrict__ dst,
    int tid, bool active, size_t nodeOff)
{
    float acc[HID];
    #pragma unroll
    for (int q = 0; q < 16; ++q) {
        float4 bb = reinterpret_cast<const float4*>(b)[q];
        acc[4*q+0] = bb.x; acc[4*q+1] = bb.y; acc[4*q+2] = bb.z; acc[4*q+3] = bb.w;
    }
    for (int k = 0; k < HID; ++k) {
        float xk = src[k][tid];
        const float4* Wr = reinterpret_cast<const float4*>(W + (k << 6));
        #pragma unroll
        for (int q = 0; q < 16; ++q) {
            float4 w = Wr[q];
            acc[4*q+0] = fmaf(xk, w.x, acc[4*q+0]);
            acc[4*q+1] = fmaf(xk, w.y, acc[4*q+1]);
            acc[4*q+2] = fmaf(xk, w.z, acc[4*q+2]);
            acc[4*q+3] = fmaf(xk, w.w, acc[4*q+3]);
        }
    }
    #pragma unroll
    for (int j = 0; j < HID; ++j) {
        gbuf[j][tid] = fmaxf(acc[j], 0.f);
        acc[j] = 0.f;
    }
    for (int k = 0; k < HID; ++k) {
        float gk = gbuf[k][tid];
        const float4* Ar = reinterpret_cast<const float4*>(A + (k << 6));
        #pragma unroll
        for (int q = 0; q < 16; ++q) {
            float4 w = Ar[q];
            acc[4*q+0] = fmaf(gk, w.x, acc[4*q+0]);
            acc[4*q+1] = fmaf(gk, w.y, acc[4*q+1]);
            acc[4*q+2] = fmaf(gk, w.z, acc[4*q+2]);
            acc[4*q+3] = fmaf(gk, w.w, acc[4*q+3]);
        }
    }
    if (active) {
        uint4* d4 = reinterpret_cast<uint4*>(dst + nodeOff);
        #pragma unroll
        for (int g = 0; g < 8; ++g) {
            union { uint4 q; ushort s[8]; } pk;
            #pragma unroll
            for (int t = 0; t < 8; ++t) {
                bf16 h = __float2bfloat16(acc[g*8 + t]);
                pk.s[t] = *reinterpret_cast<ushort*>(&h);
            }
            d4[g] = pk.q;
        }
    }
}

__global__ __launch_bounds__(NODE_BLK) void node_mlp_kernel(
    const float* __restrict__ x,
    const float* __restrict__ W1, const float* __restrict__ b1,
    const float* __restrict__ W2, const float* __restrict__ b2,
    const float* __restrict__ A12,
    bf16* __restrict__ u, bf16* __restrict__ v,
    float* __restrict__ out, int mode, int n)
{
    __shared__ float x_lds[HID][NODE_BLK];
    __shared__ float g_lds[HID][NODE_BLK];
    int tid = threadIdx.x;
    int node = blockIdx.x * NODE_BLK + tid;
    bool active = node < n;
    size_t off = (size_t)node * HID;

    if (active) {
        const float4* x4 = reinterpret_cast<const float4*>(x + off);
        float4* o4 = reinterpret_cast<float4*>(out + off);
        #pragma unroll
        for (int q = 0; q < 16; ++q) {
            float4 t = x4[q];
            x_lds[4*q+0][tid] = t.x; x_lds[4*q+1][tid] = t.y;
            x_lds[4*q+2][tid] = t.z; x_lds[4*q+3][tid] = t.w;
            if (mode == 0) o4[q] = t;
        }
    }
    gemv_pair(x_lds, g_lds, W1, b1, A12,             u, tid, active, off);
    gemv_pair(x_lds, g_lds, W2, b2, A12 + HID*HID,   v, tid, active, off);
}

// ---------------------------------------------------------------------------
// CSR build: histogram -> 2-level exclusive scan -> scatter
// ---------------------------------------------------------------------------
__global__ __launch_bounds__(256) void hist_kernel(const int* __restrict__ row,
                                                   int* __restrict__ cnt, int E)
{
    int e = blockIdx.x * 256 + threadIdx.x;
    if (e < E) atomicAdd(&cnt[row[e]], 1);
}

__global__ __launch_bounds__(SCAN_B) void scan1_kernel(const int* __restrict__ cnt,
                                                       int* __restrict__ ptr,
                                                       int* __restrict__ bsum, int n)
{
    __shared__ int lds[SCAN_B];
    int i = blockIdx.x * SCAN_B + threadIdx.x;
    int vin = (i < n) ? cnt[i] : 0;
    int val = vin;
    lds[threadIdx.x] = val;
    __syncthreads();
    for (int off = 1; off < SCAN_B; off <<= 1) {
        int t = (threadIdx.x >= off) ? lds[threadIdx.x - off] : 0;
        __syncthreads();
        val += t;
        lds[threadIdx.x] = val;
        __syncthreads();
    }
    if (i < n) ptr[i] = val - vin;
    if (threadIdx.x == SCAN_B - 1) bsum[blockIdx.x] = val;
}

__global__ __launch_bounds__(1024) void scan2_kernel(const int* __restrict__ bsum,
                                                     int* __restrict__ boffs, int nb)
{
    __shared__ int lds[1024];
    int i = threadIdx.x;
    int vin = (i < nb) ? bsum[i] : 0;
    int val = vin;
    lds[i] = val;
    __syncthreads();
    for (int off = 1; off < 1024; off <<= 1) {
        int t = (i >= off) ? lds[i - off] : 0;
        __syncthreads();
        val += t;
        lds[i] = val;
        __syncthreads();
    }
    if (i < nb) boffs[i] = val - vin;
}

__global__ __launch_bounds__(SCAN_B) void scan3_kernel(int* __restrict__ ptr,
                                                       const int* __restrict__ boffs,
                                                       int n, int E)
{
    int i = blockIdx.x * SCAN_B + threadIdx.x;
    if (i < n) ptr[i] += boffs[blockIdx.x];
    if (i == 0) ptr[n] = E;
}

__global__ __launch_bounds__(256) void scatter_kernel(const int* __restrict__ row,
                                                      const int* __restrict__ col,
                                                      int* __restrict__ wpos,
                                                      int* __restrict__ col_sorted, int E)
{
    int e = blockIdx.x * 256 + threadIdx.x;
    if (e >= E) return;
    int r = row[e];
    int pos = atomicAdd(&wpos[r], 1);
    col_sorted[pos] = col[e];
}

// ---------------------------------------------------------------------------
// Per-layer edge passes, wave-per-node over CSR. No atomics.
// ---------------------------------------------------------------------------
__global__ __launch_bounds__(256) void edge_mask_csr(
    const bf16* __restrict__ u, const bf16* __restrict__ v,
    const float* __restrict__ ab, const float* __restrict__ w2,
    const float* __restrict__ b2p,
    const int* __restrict__ ptr, const int* __restrict__ col_sorted,
    float* __restrict__ mask_sorted, float* __restrict__ rowsum, int n)
{
    int wid = (blockIdx.x * 256 + threadIdx.x) >> 6;
    if (wid >= n) return;
    int lane = threadIdx.x & 63;
    int start = ptr[wid], end = ptr[wid + 1];
    int deg = end - start;
    float uplus = __bfloat162float(u[(size_t)wid * HID + lane]) + ab[lane];
    float w2l = w2[lane];
    float b2 = b2p[0];
    float msum = 0.f;
    for (int base = 0; base < deg; base += 64) {
        int mcnt = min(64, deg - base);
        int cc = (lane < mcnt) ? col_sorted[start + base + lane] : 0;
        float mlane = 0.f;
        for (int j = 0; j < mcnt; ++j) {
            int c = __shfl(cc, j, 64);
            float h = uplus + __bfloat162float(v[(size_t)c * HID + lane]);
            float p = fmaxf(h, 0.f) * w2l;
            #pragma unroll
            for (int off = 32; off; off >>= 1) p += __shfl_xor(p, off, 64);
            float la = p + b2;
            float s = 1.f / (1.f + __expf(-la));
            float m = fminf(fmaxf(fmaf(s, 1.5f, -0.45f), 0.f), 1.f);
            msum += m;
            mlane = (lane == j) ? m : mlane;
        }
        if (lane < mcnt) mask_sorted[start + base + lane] = mlane;
    }
    if (lane == 0) rowsum[wid] = msum;
}

__global__ __launch_bounds__(256) void dinv_kernel(float* __restrict__ rs, int n)
{
    int i = blockIdx.x * 256 + threadIdx.x;
    if (i >= n) return;
    float r = rs[i] + 1e-6f;
    float d = 1.f / sqrtf(r);
    rs[i] = fminf(d, 10.f);
}

__global__ __launch_bounds__(256) void agg_csr(
    const float* __restrict__ x,
    const float* __restrict__ mask_sorted, const float* __restrict__ dinv,
    const int* __restrict__ ptr, const int* __restrict__ col_sorted,
    float* __restrict__ xnew, float* __restrict__ out, int n)
{
    int wid = (blockIdx.x * 256 + threadIdx.x) >> 6;
    if (wid >= n) return;
    int lane = threadIdx.x & 63;
    int start = ptr[wid], end = ptr[wid + 1];
    int deg = end - start;
    float acc = 0.f;
    for (int base = 0; base < deg; base += 64) {
        int mcnt = min(64, deg - base);
        int cc = 0; float wv = 0.f;
        if (lane < mcnt) {
            cc = col_sorted[start + base + lane];
            wv = mask_sorted[start + base + lane] * dinv[cc];
        }
        for (int j = 0; j < mcnt; ++j) {
            int c = __shfl(cc, j, 64);
            float wj = __shfl(wv, j, 64);
            acc = fmaf(wj, x[(size_t)c * HID + lane], acc);
        }
    }
    float res = acc * dinv[wid];
    size_t o = (size_t)wid * HID + lane;
    xnew[o] = res;
    out[o] += res;
}

// ---------------------------------------------------------------------------

extern "C" void kernel_launch(void* const* d_in, const int* in_sizes, int n_in,
                              void* d_out, int out_size, void* d_ws, size_t ws_size,
                              hipStream_t stream)
{
    const float* feat  = (const float*)d_in[0];
    const float* nbW   = (const float*)d_in[1];
    const float* nbb   = (const float*)d_in[2];
    const float* selfW = (const float*)d_in[3];
    const float* selfb = (const float*)d_in[4];
    const float* a1W   = (const float*)d_in[5];
    const float* a1b   = (const float*)d_in[6];
    const float* a2W   = (const float*)d_in[7];
    const float* a2b   = (const float*)d_in[8];
    const int*   row   = (const int*)d_in[9];
    const int*   col   = (const int*)d_in[10];
    float* out = (float*)d_out;

    const int n = in_sizes[0] / HID;
    const int E = in_sizes[9];
    const int L = in_sizes[1] / (HID * HID);
    const size_t NH = (size_t)n * HID;

    // workspace layout (~88 MB)
    char* p = (char*)d_ws;
    bf16*  u           = (bf16*)p;  p += NH * 2;
    bf16*  v           = (bf16*)p;  p += NH * 2;
    float* xb0         = (float*)p; p += NH * 4;
    float* xb1         = (float*)p; p += NH * 4;
    float* dinv        = (float*)p; p += (size_t)n * 4;
    float* mask_sorted = (float*)p; p += (size_t)E * 4;
    int*   col_sorted  = (int*)p;   p += (size_t)E * 4;
    int*   ptr         = (int*)p;   p += (size_t)(n + 1) * 4;
    int*   cnt         = (int*)p;   p += (size_t)n * 4;
    int*   bsum        = (int*)p;   p += 1024 * 4;
    int*   boffs       = (int*)p;   p += 1024 * 4;

    const int eBlocks = (E + 255) / 256;
    const int sBlocks = (n + SCAN_B - 1) / SCAN_B;   // must be <= 1024
    const int wBlocks = (int)(((size_t)n * 64 + 255) / 256);

    // ---- build CSR once (reused by all layers) ----
    hipMemsetAsync(cnt, 0, (size_t)n * sizeof(int), stream);
    hist_kernel<<<eBlocks, 256, 0, stream>>>(row, cnt, E);
    scan1_kernel<<<sBlocks, SCAN_B, 0, stream>>>(cnt, ptr, bsum, n);
    scan2_kernel<<<1, 1024, 0, stream>>>(bsum, boffs, sBlocks);
    scan3_kernel<<<sBlocks, SCAN_B, 0, stream>>>(ptr, boffs, n, E);
    hipMemcpyAsync(cnt, ptr, (size_t)n * sizeof(int), hipMemcpyDeviceToDevice, stream);
    scatter_kernel<<<eBlocks, 256, 0, stream>>>(row, col, cnt, col_sorted, E);

    // ---- layers ----
    const float* x_in = feat;
    float* x_out = xb0;
    for (int l = 0; l < L; ++l) {
        node_mlp_kernel<<<(n + NODE_BLK - 1) / NODE_BLK, NODE_BLK, 0, stream>>>(
            x_in,
            nbW + (size_t)l * HID * HID,   nbb + (size_t)l * HID,
            selfW + (size_t)l * HID * HID, selfb + (size_t)l * HID,
            a1W + (size_t)l * 2 * HID * HID,
            u, v, out, (l == 0) ? 0 : 1, n);

        edge_mask_csr<<<wBlocks, 256, 0, stream>>>(
            u, v, a1b + (size_t)l * HID, a2W + (size_t)l * HID, a2b + l,
            ptr, col_sorted, mask_sorted, dinv, n);

        dinv_kernel<<<(n + 255) / 256, 256, 0, stream>>>(dinv, n);

        agg_csr<<<wBlocks, 256, 0, stream>>>(
            x_in, mask_sorted, dinv, ptr, col_sorted, x_out, out, n);

        x_in = x_out;
        x_out = (x_out == xb0) ? xb1 : xb0;
    }
}

// Round 3
// 671.774 us; speedup vs baseline: 2.9698x; 1.7831x over previous
//
#include <hip/hip_runtime.h>
#include <hip/hip_bf16.h>
#include <math.h>

#define HID 64
#define SCAN_B 256

typedef __attribute__((ext_vector_type(4))) float f32x4;
typedef __attribute__((ext_vector_type(4))) short s16x4;

__device__ __forceinline__ ushort f2b(float x) {
    __hip_bfloat16 h = __float2bfloat16(x);
    return *reinterpret_cast<ushort*>(&h);
}
__device__ __forceinline__ float b2f(ushort u) {
    return __uint_as_float(((unsigned)u) << 16);
}

// D = A*B + C, 16x16x16 bf16 MFMA. s_nop covers VALU-write -> MFMA-read hazard.
__device__ __forceinline__ f32x4 mfma16(s16x4 a, s16x4 b, f32x4 c) {
    asm("s_nop 1\n\tv_mfma_f32_16x16x16_bf16 %0, %1, %2, %0"
        : "+v"(c) : "v"(a), "v"(b));
    return c;
}

// ---------------------------------------------------------------------------
// MFMA node MLP. Block = 256 thr (4 waves), M-tile = 128 nodes (wave: 32 rows).
// Stages: g1=relu(x@W1+b1) -> u'=g1@Atop+att1_b ; g2=relu(x@W2+b2) -> v=g2@Abot
// W matrices staged transposed in LDS (Wt[col][k], bf16, pad 68).
// Fragment layout (v_mfma_f32_16x16x16_bf16):
//   A: row=lane%16, k=4*(lane/16)+j   B: k=4*(lane/16)+j, col=lane%16
//   C: row=4*(lane/16)+j, col=lane%16
// ---------------------------------------------------------------------------
template<bool A_FROM_REGS, bool STORE_GLOBAL>
__device__ __forceinline__ void mfma_stage(
    const s16x4 afr[2][4], const ushort (*Wt)[68], const float* bias,
    ushort (*gld)[68], int w, int l, ushort* dstg, int rbase, int n)
{
    f32x4 acc[2][4];
    #pragma unroll
    for (int ct = 0; ct < 4; ++ct) {
        float bv = bias ? bias[(ct << 4) + (l & 15)] : 0.f;
        acc[0][ct] = (f32x4){bv, bv, bv, bv};
        acc[1][ct] = (f32x4){bv, bv, bv, bv};
    }
    #pragma unroll
    for (int kc = 0; kc < 4; ++kc) {
        s16x4 a0, a1;
        if (A_FROM_REGS) {
            a0 = afr[0][kc]; a1 = afr[1][kc];
        } else {
            a0 = *(const s16x4*)&gld[w*32 +  0 + (l & 15)][((l >> 4) << 2) + (kc << 4)];
            a1 = *(const s16x4*)&gld[w*32 + 16 + (l & 15)][((l >> 4) << 2) + (kc << 4)];
        }
        #pragma unroll
        for (int ct = 0; ct < 4; ++ct) {
            s16x4 b = *(const s16x4*)&Wt[(ct << 4) + (l & 15)][((l >> 4) << 2) + (kc << 4)];
            acc[0][ct] = mfma16(a0, b, acc[0][ct]);
            acc[1][ct] = mfma16(a1, b, acc[1][ct]);
        }
    }
    asm volatile("s_nop 7\n\ts_nop 7");   // MFMA-write -> VALU-read hazard
    #pragma unroll
    for (int rt = 0; rt < 2; ++rt)
    #pragma unroll
    for (int ct = 0; ct < 4; ++ct)
    #pragma unroll
    for (int j = 0; j < 4; ++j) {
        int rloc = w*32 + rt*16 + ((l >> 4) << 2) + j;
        if (STORE_GLOBAL) {
            int rg = rbase + rloc;
            if (rg < n)
                dstg[(size_t)rg * HID + (ct << 4) + (l & 15)] = f2b(acc[rt][ct][j]);
        } else {
            gld[rloc][(ct << 4) + (l & 15)] = f2b(fmaxf(acc[rt][ct][j], 0.f));
        }
    }
}

__global__ __launch_bounds__(256) void node_mlp_mfma(
    const float* __restrict__ x,
    const float* __restrict__ W1, const float* __restrict__ b1,
    const float* __restrict__ W2, const float* __restrict__ b2,
    const float* __restrict__ A12,   // [128][64]: top then bottom
    const float* __restrict__ ab,    // att1_b (folded into u)
    ushort* __restrict__ u, ushort* __restrict__ v, int n)
{
    __shared__ ushort Wt[4][64][68];
    __shared__ ushort gld[128][68];
    int tid = threadIdx.x;
    int l = tid & 63, w = tid >> 6;
    int rbase = blockIdx.x * 128;

    // stage the 4 weight matrices transposed (bf16)
    const float* Wsrc[4] = { W1, A12, W2, A12 + HID*HID };
    for (int m = 0; m < 4; ++m) {
        const float4* s4 = reinterpret_cast<const float4*>(Wsrc[m]);
        #pragma unroll
        for (int q = 0; q < 4; ++q) {
            float4 t = s4[tid*4 + q];
            int idx = tid*16 + q*4;
            int k = idx >> 6, c = idx & 63;
            Wt[m][c+0][k] = f2b(t.x); Wt[m][c+1][k] = f2b(t.y);
            Wt[m][c+2][k] = f2b(t.z); Wt[m][c+3][k] = f2b(t.w);
        }
    }

    // x A-fragments straight from global
    s16x4 afr[2][4];
    #pragma unroll
    for (int rt = 0; rt < 2; ++rt) {
        int r = rbase + w*32 + rt*16 + (l & 15);
        int rc = min(r, n - 1);
        const float4* xr = reinterpret_cast<const float4*>(x + (size_t)rc * HID + ((l >> 4) << 2));
        #pragma unroll
        for (int kc = 0; kc < 4; ++kc) {
            float4 t = xr[kc * 4];
            s16x4 a;
            a[0] = (short)f2b(t.x); a[1] = (short)f2b(t.y);
            a[2] = (short)f2b(t.z); a[3] = (short)f2b(t.w);
            afr[rt][kc] = a;
        }
    }
    __syncthreads();

    mfma_stage<true,  false>(afr, Wt[0], b1,      gld, w, l, nullptr, rbase, n); // g1
    mfma_stage<false, true >(afr, Wt[1], ab,      gld, w, l, u,       rbase, n); // u'=g1@Atop+ab
    mfma_stage<true,  false>(afr, Wt[2], b2,      gld, w, l, nullptr, rbase, n); // g2
    mfma_stage<false, true >(afr, Wt[3], nullptr, gld, w, l, v,       rbase, n); // v =g2@Abot
}

// ---------------------------------------------------------------------------
// CSR build: histogram -> 2-level exclusive scan -> scatter (row & col)
// ---------------------------------------------------------------------------
__global__ __launch_bounds__(256) void hist_kernel(const int* __restrict__ row,
                                                   int* __restrict__ cnt, int E)
{
    int e = blockIdx.x * 256 + threadIdx.x;
    if (e < E) atomicAdd(&cnt[row[e]], 1);
}

__global__ __launch_bounds__(SCAN_B) void scan1_kernel(const int* __restrict__ cnt,
                                                       int* __restrict__ ptr,
                                                       int* __restrict__ bsum, int n)
{
    __shared__ int lds[SCAN_B];
    int i = blockIdx.x * SCAN_B + threadIdx.x;
    int vin = (i < n) ? cnt[i] : 0;
    int val = vin;
    lds[threadIdx.x] = val;
    __syncthreads();
    for (int off = 1; off < SCAN_B; off <<= 1) {
        int t = (threadIdx.x >= off) ? lds[threadIdx.x - off] : 0;
        __syncthreads();
        val += t;
        lds[threadIdx.x] = val;
        __syncthreads();
    }
    if (i < n) ptr[i] = val - vin;
    if (threadIdx.x == SCAN_B - 1) bsum[blockIdx.x] = val;
}

__global__ __launch_bounds__(1024) void scan2_kernel(const int* __restrict__ bsum,
                                                     int* __restrict__ boffs, int nb)
{
    __shared__ int lds[1024];
    int i = threadIdx.x;
    int vin = (i < nb) ? bsum[i] : 0;
    int val = vin;
    lds[i] = val;
    __syncthreads();
    for (int off = 1; off < 1024; off <<= 1) {
        int t = (i >= off) ? lds[i - off] : 0;
        __syncthreads();
        val += t;
        lds[i] = val;
        __syncthreads();
    }
    if (i < nb) boffs[i] = val - vin;
}

__global__ __launch_bounds__(SCAN_B) void scan3_kernel(int* __restrict__ ptr,
                                                       const int* __restrict__ boffs,
                                                       int n, int E)
{
    int i = blockIdx.x * SCAN_B + threadIdx.x;
    if (i < n) ptr[i] += boffs[blockIdx.x];
    if (i == 0) ptr[n] = E;
}

__global__ __launch_bounds__(256) void scatter_kernel(const int* __restrict__ row,
                                                      const int* __restrict__ col,
                                                      int* __restrict__ wpos,
                                                      int* __restrict__ col_sorted,
                                                      int* __restrict__ row_sorted, int E)
{
    int e = blockIdx.x * 256 + threadIdx.x;
    if (e >= E) return;
    int r = row[e];
    int pos = atomicAdd(&wpos[r], 1);
    col_sorted[pos] = col[e];
    row_sorted[pos] = r;
}

// ---------------------------------------------------------------------------
// Edge mask: 16 lanes per edge. h = relu(u'[r]+v[c]); la = h.w2 + b2
// ---------------------------------------------------------------------------
__global__ __launch_bounds__(256) void edge_mask16(
    const ushort* __restrict__ u, const ushort* __restrict__ v,
    const float* __restrict__ w2, const float* __restrict__ b2p,
    const int* __restrict__ rows, const int* __restrict__ cols,
    float* __restrict__ mask_sorted, int E)
{
    int g = (blockIdx.x * 256 + threadIdx.x) >> 4;
    if (g >= E) return;
    int sub = threadIdx.x & 15;
    int r = rows[g], c = cols[g];
    ushort4 uu = *reinterpret_cast<const ushort4*>(u + (size_t)r * HID + sub * 4);
    ushort4 vv = *reinterpret_cast<const ushort4*>(v + (size_t)c * HID + sub * 4);
    float4 ww = *reinterpret_cast<const float4*>(w2 + sub * 4);
    float p = fmaxf(b2f(uu.x) + b2f(vv.x), 0.f) * ww.x;
    p = fmaf(fmaxf(b2f(uu.y) + b2f(vv.y), 0.f), ww.y, p);
    p = fmaf(fmaxf(b2f(uu.z) + b2f(vv.z), 0.f), ww.z, p);
    p = fmaf(fmaxf(b2f(uu.w) + b2f(vv.w), 0.f), ww.w, p);
    p += __shfl_xor(p, 1, 64);
    p += __shfl_xor(p, 2, 64);
    p += __shfl_xor(p, 4, 64);
    p += __shfl_xor(p, 8, 64);
    if (sub == 0) {
        float la = p + b2p[0];
        float s = 1.f / (1.f + __expf(-la));
        mask_sorted[g] = fminf(fmaxf(fmaf(s, 1.5f, -0.45f), 0.f), 1.f);
    }
}

// per-node rowsum over sorted masks, fused with d^-1/2 (deterministic)
__global__ __launch_bounds__(256) void rowsum_dinv(
    const float* __restrict__ mask_sorted, const int* __restrict__ ptr,
    float* __restrict__ dinv, int n)
{
    int i = blockIdx.x * 256 + threadIdx.x;
    if (i >= n) return;
    int s0 = ptr[i], s1 = ptr[i + 1];
    float s = 1e-6f;
    for (int e = s0; e < s1; ++e) s += mask_sorted[e];
    float d = 1.f / sqrtf(s);
    dinv[i] = fminf(d, 10.f);
}

// wave-per-node aggregation (unchanged)
__global__ __launch_bounds__(256) void agg_csr(
    const float* __restrict__ x,
    const float* __restrict__ mask_sorted, const float* __restrict__ dinv,
    const int* __restrict__ ptr, const int* __restrict__ col_sorted,
    float* __restrict__ xnew, float* __restrict__ out, int n)
{
    int wid = (blockIdx.x * 256 + threadIdx.x) >> 6;
    if (wid >= n) return;
    int lane = threadIdx.x & 63;
    int start = ptr[wid], end = ptr[wid + 1];
    int deg = end - start;
    float acc = 0.f;
    for (int base = 0; base < deg; base += 64) {
        int mcnt = min(64, deg - base);
        int cc = 0; float wv = 0.f;
        if (lane < mcnt) {
            cc = col_sorted[start + base + lane];
            wv = mask_sorted[start + base + lane] * dinv[cc];
        }
        for (int j = 0; j < mcnt; ++j) {
            int c = __shfl(cc, j, 64);
            float wj = __shfl(wv, j, 64);
            acc = fmaf(wj, x[(size_t)c * HID + lane], acc);
        }
    }
    float res = acc * dinv[wid];
    size_t o = (size_t)wid * HID + lane;
    xnew[o] = res;
    out[o] += res;
}

// ---------------------------------------------------------------------------

extern "C" void kernel_launch(void* const* d_in, const int* in_sizes, int n_in,
                              void* d_out, int out_size, void* d_ws, size_t ws_size,
                              hipStream_t stream)
{
    const float* feat  = (const float*)d_in[0];
    const float* nbW   = (const float*)d_in[1];
    const float* nbb   = (const float*)d_in[2];
    const float* selfW = (const float*)d_in[3];
    const float* selfb = (const float*)d_in[4];
    const float* a1W   = (const float*)d_in[5];
    const float* a1b   = (const float*)d_in[6];
    const float* a2W   = (const float*)d_in[7];
    const float* a2b   = (const float*)d_in[8];
    const int*   row   = (const int*)d_in[9];
    const int*   col   = (const int*)d_in[10];
    float* out = (float*)d_out;

    const int n = in_sizes[0] / HID;
    const int E = in_sizes[9];
    const int L = in_sizes[1] / (HID * HID);
    const size_t NH = (size_t)n * HID;

    char* p = (char*)d_ws;
    ushort* u          = (ushort*)p; p += NH * 2;
    ushort* v          = (ushort*)p; p += NH * 2;
    float* xb0         = (float*)p;  p += NH * 4;
    float* xb1         = (float*)p;  p += NH * 4;
    float* dinv        = (float*)p;  p += (size_t)n * 4;
    float* mask_sorted = (float*)p;  p += (size_t)E * 4;
    int*   col_sorted  = (int*)p;    p += (size_t)E * 4;
    int*   row_sorted  = (int*)p;    p += (size_t)E * 4;
    int*   ptr         = (int*)p;    p += (size_t)(n + 1) * 4;
    int*   cnt         = (int*)p;    p += (size_t)n * 4;
    int*   bsum        = (int*)p;    p += 1024 * 4;
    int*   boffs       = (int*)p;    p += 1024 * 4;

    const int eBlocks = (E + 255) / 256;
    const int sBlocks = (n + SCAN_B - 1) / SCAN_B;
    const int wBlocks = (int)(((size_t)n * 64 + 255) / 256);
    const int mBlocks = (E + 15) / 16;
    const int nodeBlocks = (n + 127) / 128;

    // CSR build (once, reused by all layers)
    hipMemsetAsync(cnt, 0, (size_t)n * sizeof(int), stream);
    hist_kernel<<<eBlocks, 256, 0, stream>>>(row, cnt, E);
    scan1_kernel<<<sBlocks, SCAN_B, 0, stream>>>(cnt, ptr, bsum, n);
    scan2_kernel<<<1, 1024, 0, stream>>>(bsum, boffs, sBlocks);
    scan3_kernel<<<sBlocks, SCAN_B, 0, stream>>>(ptr, boffs, n, E);
    hipMemcpyAsync(cnt, ptr, (size_t)n * sizeof(int), hipMemcpyDeviceToDevice, stream);
    scatter_kernel<<<eBlocks, 256, 0, stream>>>(row, col, cnt, col_sorted, row_sorted, E);

    // out = features
    hipMemcpyAsync(out, feat, NH * sizeof(float), hipMemcpyDeviceToDevice, stream);

    const float* x_in = feat;
    float* x_out = xb0;
    for (int l = 0; l < L; ++l) {
        node_mlp_mfma<<<nodeBlocks, 256, 0, stream>>>(
            x_in,
            nbW + (size_t)l * HID * HID,   nbb + (size_t)l * HID,
            selfW + (size_t)l * HID * HID, selfb + (size_t)l * HID,
            a1W + (size_t)l * 2 * HID * HID,
            a1b + (size_t)l * HID,
            u, v, n);

        edge_mask16<<<mBlocks, 256, 0, stream>>>(
            u, v, a2W + (size_t)l * HID, a2b + l,
            row_sorted, col_sorted, mask_sorted, E);

        rowsum_dinv<<<(n + 255) / 256, 256, 0, stream>>>(mask_sorted, ptr, dinv, n);

        agg_csr<<<wBlocks, 256, 0, stream>>>(
            x_in, mask_sorted, dinv, ptr, col_sorted, x_out, out, n);

        x_in = x_out;
        x_out = (x_out == xb0) ? xb1 : xb0;
    }
}

// Round 4
// 658.972 us; speedup vs baseline: 3.0275x; 1.0194x over previous
//
#include <hip/hip_runtime.h>
#include <hip/hip_bf16.h>
#include <math.h>

#define HID 64
#define SCAN_B 256

typedef __attribute__((ext_vector_type(4))) float f32x4;
typedef __attribute__((ext_vector_type(4))) short s16x4;

__device__ __forceinline__ ushort f2b(float x) {
    __hip_bfloat16 h = __float2bfloat16(x);
    return *reinterpret_cast<ushort*>(&h);
}
__device__ __forceinline__ float b2f(ushort u) {
    return __uint_as_float(((unsigned)u) << 16);
}

// D = A*B + C, 16x16x16 bf16 MFMA. s_nop covers VALU-write -> MFMA-read hazard.
__device__ __forceinline__ f32x4 mfma16(s16x4 a, s16x4 b, f32x4 c) {
    asm("s_nop 1\n\tv_mfma_f32_16x16x16_bf16 %0, %1, %2, %0"
        : "+v"(c) : "v"(a), "v"(b));
    return c;
}

// ---------------------------------------------------------------------------
// feat (f32) -> bf16 copy, 8 elems/thread
// ---------------------------------------------------------------------------
__global__ __launch_bounds__(256) void cvt_bf16_kernel(const float* __restrict__ x,
                                                       ushort* __restrict__ x16, long n8)
{
    long i = (long)blockIdx.x * 256 + threadIdx.x;
    if (i >= n8) return;
    const float4* s = reinterpret_cast<const float4*>(x) + i * 2;
    float4 a = s[0], b = s[1];
    union { uint4 q; ushort s[8]; } pk;
    pk.s[0] = f2b(a.x); pk.s[1] = f2b(a.y); pk.s[2] = f2b(a.z); pk.s[3] = f2b(a.w);
    pk.s[4] = f2b(b.x); pk.s[5] = f2b(b.y); pk.s[6] = f2b(b.z); pk.s[7] = f2b(b.w);
    reinterpret_cast<uint4*>(x16)[i] = pk.q;
}

// ---------------------------------------------------------------------------
// MFMA node MLP. Block = 256 thr (4 waves), M-tile = 128 nodes (wave: 32 rows).
// x now read directly as bf16.
// ---------------------------------------------------------------------------
template<bool A_FROM_REGS, bool STORE_GLOBAL>
__device__ __forceinline__ void mfma_stage(
    const s16x4 afr[2][4], const ushort (*Wt)[68], const float* bias,
    ushort (*gld)[68], int w, int l, ushort* dstg, int rbase, int n)
{
    f32x4 acc[2][4];
    #pragma unroll
    for (int ct = 0; ct < 4; ++ct) {
        float bv = bias ? bias[(ct << 4) + (l & 15)] : 0.f;
        acc[0][ct] = (f32x4){bv, bv, bv, bv};
        acc[1][ct] = (f32x4){bv, bv, bv, bv};
    }
    #pragma unroll
    for (int kc = 0; kc < 4; ++kc) {
        s16x4 a0, a1;
        if (A_FROM_REGS) {
            a0 = afr[0][kc]; a1 = afr[1][kc];
        } else {
            a0 = *(const s16x4*)&gld[w*32 +  0 + (l & 15)][((l >> 4) << 2) + (kc << 4)];
            a1 = *(const s16x4*)&gld[w*32 + 16 + (l & 15)][((l >> 4) << 2) + (kc << 4)];
        }
        #pragma unroll
        for (int ct = 0; ct < 4; ++ct) {
            s16x4 b = *(const s16x4*)&Wt[(ct << 4) + (l & 15)][((l >> 4) << 2) + (kc << 4)];
            acc[0][ct] = mfma16(a0, b, acc[0][ct]);
            acc[1][ct] = mfma16(a1, b, acc[1][ct]);
        }
    }
    asm volatile("s_nop 7\n\ts_nop 7");   // MFMA-write -> VALU-read hazard
    #pragma unroll
    for (int rt = 0; rt < 2; ++rt)
    #pragma unroll
    for (int ct = 0; ct < 4; ++ct)
    #pragma unroll
    for (int j = 0; j < 4; ++j) {
        int rloc = w*32 + rt*16 + ((l >> 4) << 2) + j;
        if (STORE_GLOBAL) {
            int rg = rbase + rloc;
            if (rg < n)
                dstg[(size_t)rg * HID + (ct << 4) + (l & 15)] = f2b(acc[rt][ct][j]);
        } else {
            gld[rloc][(ct << 4) + (l & 15)] = f2b(fmaxf(acc[rt][ct][j], 0.f));
        }
    }
}

__global__ __launch_bounds__(256) void node_mlp_mfma(
    const ushort* __restrict__ x16,
    const float* __restrict__ W1, const float* __restrict__ b1,
    const float* __restrict__ W2, const float* __restrict__ b2,
    const float* __restrict__ A12,
    const float* __restrict__ ab,
    ushort* __restrict__ u, ushort* __restrict__ v, int n)
{
    __shared__ ushort Wt[4][64][68];
    __shared__ ushort gld[128][68];
    int tid = threadIdx.x;
    int l = tid & 63, w = tid >> 6;
    int rbase = blockIdx.x * 128;

    const float* Wsrc[4] = { W1, A12, W2, A12 + HID*HID };
    for (int m = 0; m < 4; ++m) {
        const float4* s4 = reinterpret_cast<const float4*>(Wsrc[m]);
        #pragma unroll
        for (int q = 0; q < 4; ++q) {
            float4 t = s4[tid*4 + q];
            int idx = tid*16 + q*4;
            int k = idx >> 6, c = idx & 63;
            Wt[m][c+0][k] = f2b(t.x); Wt[m][c+1][k] = f2b(t.y);
            Wt[m][c+2][k] = f2b(t.z); Wt[m][c+3][k] = f2b(t.w);
        }
    }

    // x A-fragments straight from global (bf16)
    s16x4 afr[2][4];
    #pragma unroll
    for (int rt = 0; rt < 2; ++rt) {
        int r = rbase + w*32 + rt*16 + (l & 15);
        int rc = min(r, n - 1);
        const ushort* xr = x16 + (size_t)rc * HID + ((l >> 4) << 2);
        #pragma unroll
        for (int kc = 0; kc < 4; ++kc)
            afr[rt][kc] = *(const s16x4*)(xr + (kc << 4));
    }
    __syncthreads();

    mfma_stage<true,  false>(afr, Wt[0], b1,      gld, w, l, nullptr, rbase, n);
    mfma_stage<false, true >(afr, Wt[1], ab,      gld, w, l, u,       rbase, n);
    mfma_stage<true,  false>(afr, Wt[2], b2,      gld, w, l, nullptr, rbase, n);
    mfma_stage<false, true >(afr, Wt[3], nullptr, gld, w, l, v,       rbase, n);
}

// ---------------------------------------------------------------------------
// CSR build
// ---------------------------------------------------------------------------
__global__ __launch_bounds__(256) void hist_kernel(const int* __restrict__ row,
                                                   int* __restrict__ cnt, int E)
{
    int e = blockIdx.x * 256 + threadIdx.x;
    if (e < E) atomicAdd(&cnt[row[e]], 1);
}

__global__ __launch_bounds__(SCAN_B) void scan1_kernel(const int* __restrict__ cnt,
                                                       int* __restrict__ ptr,
                                                       int* __restrict__ bsum, int n)
{
    __shared__ int lds[SCAN_B];
    int i = blockIdx.x * SCAN_B + threadIdx.x;
    int vin = (i < n) ? cnt[i] : 0;
    int val = vin;
    lds[threadIdx.x] = val;
    __syncthreads();
    for (int off = 1; off < SCAN_B; off <<= 1) {
        int t = (threadIdx.x >= off) ? lds[threadIdx.x - off] : 0;
        __syncthreads();
        val += t;
        lds[threadIdx.x] = val;
        __syncthreads();
    }
    if (i < n) ptr[i] = val - vin;
    if (threadIdx.x == SCAN_B - 1) bsum[blockIdx.x] = val;
}

__global__ __launch_bounds__(1024) void scan2_kernel(const int* __restrict__ bsum,
                                                     int* __restrict__ boffs, int nb)
{
    __shared__ int lds[1024];
    int i = threadIdx.x;
    int vin = (i < nb) ? bsum[i] : 0;
    int val = vin;
    lds[i] = val;
    __syncthreads();
    for (int off = 1; off < 1024; off <<= 1) {
        int t = (i >= off) ? lds[i - off] : 0;
        __syncthreads();
        val += t;
        lds[i] = val;
        __syncthreads();
    }
    if (i < nb) boffs[i] = val - vin;
}

__global__ __launch_bounds__(SCAN_B) void scan3_kernel(int* __restrict__ ptr,
                                                       const int* __restrict__ boffs,
                                                       int n, int E)
{
    int i = blockIdx.x * SCAN_B + threadIdx.x;
    if (i < n) ptr[i] += boffs[blockIdx.x];
    if (i == 0) ptr[n] = E;
}

__global__ __launch_bounds__(256) void scatter_kernel(const int* __restrict__ row,
                                                      const int* __restrict__ col,
                                                      int* __restrict__ wpos,
                                                      int* __restrict__ col_sorted,
                                                      int* __restrict__ row_sorted, int E)
{
    int e = blockIdx.x * 256 + threadIdx.x;
    if (e >= E) return;
    int r = row[e];
    int pos = atomicAdd(&wpos[r], 1);
    col_sorted[pos] = col[e];
    row_sorted[pos] = r;
}

// ---------------------------------------------------------------------------
// Edge mask: 16 lanes per edge
// ---------------------------------------------------------------------------
__global__ __launch_bounds__(256) void edge_mask16(
    const ushort* __restrict__ u, const ushort* __restrict__ v,
    const float* __restrict__ w2, const float* __restrict__ b2p,
    const int* __restrict__ rows, const int* __restrict__ cols,
    float* __restrict__ mask_sorted, int E)
{
    int g = (blockIdx.x * 256 + threadIdx.x) >> 4;
    if (g >= E) return;
    int sub = threadIdx.x & 15;
    int r = rows[g], c = cols[g];
    ushort4 uu = *reinterpret_cast<const ushort4*>(u + (size_t)r * HID + sub * 4);
    ushort4 vv = *reinterpret_cast<const ushort4*>(v + (size_t)c * HID + sub * 4);
    float4 ww = *reinterpret_cast<const float4*>(w2 + sub * 4);
    float p = fmaxf(b2f(uu.x) + b2f(vv.x), 0.f) * ww.x;
    p = fmaf(fmaxf(b2f(uu.y) + b2f(vv.y), 0.f), ww.y, p);
    p = fmaf(fmaxf(b2f(uu.z) + b2f(vv.z), 0.f), ww.z, p);
    p = fmaf(fmaxf(b2f(uu.w) + b2f(vv.w), 0.f), ww.w, p);
    p += __shfl_xor(p, 1, 64);
    p += __shfl_xor(p, 2, 64);
    p += __shfl_xor(p, 4, 64);
    p += __shfl_xor(p, 8, 64);
    if (sub == 0) {
        float la = p + b2p[0];
        float s = 1.f / (1.f + __expf(-la));
        mask_sorted[g] = fminf(fmaxf(fmaf(s, 1.5f, -0.45f), 0.f), 1.f);
    }
}

__global__ __launch_bounds__(256) void rowsum_dinv(
    const float* __restrict__ mask_sorted, const int* __restrict__ ptr,
    float* __restrict__ dinv, int n)
{
    int i = blockIdx.x * 256 + threadIdx.x;
    if (i >= n) return;
    int s0 = ptr[i], s1 = ptr[i + 1];
    float s = 1e-6f;
    for (int e = s0; e < s1; ++e) s += mask_sorted[e];
    float d = 1.f / sqrtf(s);
    dinv[i] = fminf(d, 10.f);
}

// ---------------------------------------------------------------------------
// Aggregation: wave-per-node, bf16 x gather, f32 accumulate.
// out[o] = base[o] + res (base=feat on layer 0, else out itself);
// x16_out = bf16(res) for the next layer.
// ---------------------------------------------------------------------------
__global__ __launch_bounds__(256) void agg_csr(
    const ushort* __restrict__ x16,
    const float* __restrict__ mask_sorted, const float* __restrict__ dinv,
    const int* __restrict__ ptr, const int* __restrict__ col_sorted,
    const float* __restrict__ base_in, float* __restrict__ out,
    ushort* __restrict__ x16_out, int n)
{
    int wid = (blockIdx.x * 256 + threadIdx.x) >> 6;
    if (wid >= n) return;
    int lane = threadIdx.x & 63;
    int start = ptr[wid], end = ptr[wid + 1];
    int deg = end - start;
    float acc = 0.f;
    for (int base = 0; base < deg; base += 64) {
        int mcnt = min(64, deg - base);
        int cc = 0; float wv = 0.f;
        if (lane < mcnt) {
            cc = col_sorted[start + base + lane];
            wv = mask_sorted[start + base + lane] * dinv[cc];
        }
        for (int j = 0; j < mcnt; ++j) {
            int c = __shfl(cc, j, 64);
            float wj = __shfl(wv, j, 64);
            float xv = b2f(x16[(size_t)c * HID + lane]);
            acc = fmaf(wj, xv, acc);
        }
    }
    float res = acc * dinv[wid];
    size_t o = (size_t)wid * HID + lane;
    out[o] = base_in[o] + res;
    x16_out[o] = f2b(res);
}

// ---------------------------------------------------------------------------

extern "C" void kernel_launch(void* const* d_in, const int* in_sizes, int n_in,
                              void* d_out, int out_size, void* d_ws, size_t ws_size,
                              hipStream_t stream)
{
    const float* feat  = (const float*)d_in[0];
    const float* nbW   = (const float*)d_in[1];
    const float* nbb   = (const float*)d_in[2];
    const float* selfW = (const float*)d_in[3];
    const float* selfb = (const float*)d_in[4];
    const float* a1W   = (const float*)d_in[5];
    const float* a1b   = (const float*)d_in[6];
    const float* a2W   = (const float*)d_in[7];
    const float* a2b   = (const float*)d_in[8];
    const int*   row   = (const int*)d_in[9];
    const int*   col   = (const int*)d_in[10];
    float* out = (float*)d_out;

    const int n = in_sizes[0] / HID;
    const int E = in_sizes[9];
    const int L = in_sizes[1] / (HID * HID);
    const size_t NH = (size_t)n * HID;

    char* p = (char*)d_ws;
    ushort* u          = (ushort*)p; p += NH * 2;
    ushort* v          = (ushort*)p; p += NH * 2;
    ushort* x16a       = (ushort*)p; p += NH * 2;
    ushort* x16b       = (ushort*)p; p += NH * 2;
    float* dinv        = (float*)p;  p += (size_t)n * 4;
    float* mask_sorted = (float*)p;  p += (size_t)E * 4;
    int*   col_sorted  = (int*)p;    p += (size_t)E * 4;
    int*   row_sorted  = (int*)p;    p += (size_t)E * 4;
    int*   ptr         = (int*)p;    p += (size_t)(n + 1) * 4;
    int*   cnt         = (int*)p;    p += (size_t)n * 4;
    int*   bsum        = (int*)p;    p += 1024 * 4;
    int*   boffs       = (int*)p;    p += 1024 * 4;

    const int eBlocks = (E + 255) / 256;
    const int sBlocks = (n + SCAN_B - 1) / SCAN_B;
    const int wBlocks = (int)(((size_t)n * 64 + 255) / 256);
    const int mBlocks = (E + 15) / 16;
    const int nodeBlocks = (n + 127) / 128;

    // CSR build (once)
    hipMemsetAsync(cnt, 0, (size_t)n * sizeof(int), stream);
    hist_kernel<<<eBlocks, 256, 0, stream>>>(row, cnt, E);
    scan1_kernel<<<sBlocks, SCAN_B, 0, stream>>>(cnt, ptr, bsum, n);
    scan2_kernel<<<1, 1024, 0, stream>>>(bsum, boffs, sBlocks);
    scan3_kernel<<<sBlocks, SCAN_B, 0, stream>>>(ptr, boffs, n, E);
    hipMemcpyAsync(cnt, ptr, (size_t)n * sizeof(int), hipMemcpyDeviceToDevice, stream);
    scatter_kernel<<<eBlocks, 256, 0, stream>>>(row, col, cnt, col_sorted, row_sorted, E);

    // feat -> bf16 (layer-0 x)
    cvt_bf16_kernel<<<(int)((NH / 8 + 255) / 256), 256, 0, stream>>>(feat, x16a, (long)(NH / 8));

    const ushort* x_in = x16a;
    ushort* x_out = x16b;
    for (int l = 0; l < L; ++l) {
        node_mlp_mfma<<<nodeBlocks, 256, 0, stream>>>(
            x_in,
            nbW + (size_t)l * HID * HID,   nbb + (size_t)l * HID,
            selfW + (size_t)l * HID * HID, selfb + (size_t)l * HID,
            a1W + (size_t)l * 2 * HID * HID,
            a1b + (size_t)l * HID,
            u, v, n);

        edge_mask16<<<mBlocks, 256, 0, stream>>>(
            u, v, a2W + (size_t)l * HID, a2b + l,
            row_sorted, col_sorted, mask_sorted, E);

        rowsum_dinv<<<(n + 255) / 256, 256, 0, stream>>>(mask_sorted, ptr, dinv, n);

        agg_csr<<<wBlocks, 256, 0, stream>>>(
            x_in, mask_sorted, dinv, ptr, col_sorted,
            (l == 0) ? feat : out, out, x_out, n);

        x_in = x_out;
        x_out = (x_out == x16a) ? x16a + 0 : x16a;   // ping-pong
        x_out = (x_in == x16a) ? x16b : x16a;
    }
}